// Round 1
// baseline (149.015 us; speedup 1.0000x reference)
//
#include <hip/hip_runtime.h>
#include <stdint.h>

#define D_IN  256
#define D_OUT 128
#define NSEQ  4096
#define NB    16
#define TILE_M 128
#define LDS_BYTES 65536

typedef __bf16 bf16x8 __attribute__((ext_vector_type(8)));
typedef float  f32x4  __attribute__((ext_vector_type(4)));

__device__ __forceinline__ unsigned short f2bf(float f) {
  union { float f; unsigned int u; } a; a.f = f;
  unsigned int r = a.u + 0x7FFFu + ((a.u >> 16) & 1u);
  return (unsigned short)(r >> 16);
}

// ws-layout weights: WT[n][k] bf16 (row-major in n, k contiguous)
__global__ __launch_bounds__(256) void prep_weights(
    const float* __restrict__ Wp, const float* __restrict__ W1, const float* __restrict__ W2,
    unsigned short* __restrict__ WpT, unsigned short* __restrict__ W1T, unsigned short* __restrict__ W2T) {
  int t = blockIdx.x * 256 + threadIdx.x;
  if (t < 256 * 128) {
    int k = t >> 7, n = t & 127;
    WpT[n * 256 + k] = f2bf(Wp[t]);
  } else if (t < 256 * 128 + 128 * 128) {
    int t2 = t - 256 * 128; int k = t2 >> 7, n = t2 & 127;
    W1T[n * 128 + k] = f2bf(W1[t2]);
  } else {
    int t3 = t - 256 * 128 - 128 * 128; int k = t3 >> 7, n = t3 & 127;
    W2T[n * 128 + k] = f2bf(W2[t3]);
  }
}

// LDS: two bf16 buffers [128 rows][128 elems], XOR-swizzled in 16B (8-elem)
// granules: element (row, col) lives at row*128 + ((col>>3) ^ (row&15))*8 + (col&7).
// Swizzle makes both MFMA b128 fragment reads and staging writes conflict-free.
__global__ __launch_bounds__(256, 2) void fused3(
    const float* __restrict__ X,
    const unsigned short* __restrict__ WpT,
    const unsigned short* __restrict__ W1T,
    const unsigned short* __restrict__ W2T,
    const float* __restrict__ bproj, const float* __restrict__ b1v, const float* __restrict__ b2v,
    float* __restrict__ out, float* __restrict__ S) {
  extern __shared__ char smem[];
  unsigned short* buf0 = (unsigned short*)smem;             // A operand (X / Y1 / Y2)
  unsigned short* buf1 = (unsigned short*)(smem + 32768);   // B operand (WpT / W1T / W2T)
  float* y3l = (float*)smem;                                // [128][128] fp32, spans both

  const int tid  = threadIdx.x;
  const int lane = tid & 63;
  const int w    = tid >> 6;       // wave 0..3 -> rows [32w, 32w+32)
  const int q    = lane >> 4;      // quad 0..3
  const int l16  = lane & 15;
  const int rowbase = blockIdx.x * TILE_M;
  const int bidx = rowbase >> 12;  // batch index (4096 rows per batch)

  f32x4 acc[2][8];

  // ---------------- GEMM1: Y1 = X @ Wp  (K=256, two K-chunks of 128) ----------------
#pragma unroll
  for (int rt = 0; rt < 2; ++rt)
#pragma unroll
    for (int ct = 0; ct < 8; ++ct) acc[rt][ct] = (f32x4){0.f, 0.f, 0.f, 0.f};

  for (int c = 0; c < 2; ++c) {
    if (c) __syncthreads();
    // stage X chunk (fp32 -> bf16) into buf0
#pragma unroll
    for (int it = 0; it < 16; ++it) {
      int i = tid + it * 256;
      int r = i >> 5, c4 = (i & 31) << 2;            // 32 float4 per row
      const float4 v = *(const float4*)(X + (size_t)(rowbase + r) * D_IN + c * 128 + c4);
      ushort4 u; u.x = f2bf(v.x); u.y = f2bf(v.y); u.z = f2bf(v.z); u.w = f2bf(v.w);
      int g = c4 >> 3, wi = c4 & 7;
      *(ushort4*)(buf0 + r * 128 + (((g ^ (r & 15)) << 3) + wi)) = u;
    }
    // stage Wp chunk into buf1
#pragma unroll
    for (int it = 0; it < 8; ++it) {
      int i = tid + it * 256;
      int r = i >> 4, g = i & 15;                    // 16 granules of 8 bf16 per row
      *(uint4*)(buf1 + r * 128 + ((g ^ (r & 15)) << 3)) =
          *(const uint4*)(WpT + r * 256 + c * 128 + (g << 3));
    }
    __syncthreads();
#pragma unroll
    for (int ks = 0; ks < 4; ++ks) {
      bf16x8 a0 = *(const bf16x8*)(buf0 + (w * 32 + l16) * 128      + (((4 * ks + q) ^ l16) << 3));
      bf16x8 a1 = *(const bf16x8*)(buf0 + (w * 32 + 16 + l16) * 128 + (((4 * ks + q) ^ l16) << 3));
#pragma unroll
      for (int ct = 0; ct < 8; ++ct) {
        bf16x8 b = *(const bf16x8*)(buf1 + (ct * 16 + l16) * 128 + (((4 * ks + q) ^ l16) << 3));
        acc[0][ct] = __builtin_amdgcn_mfma_f32_16x16x32_bf16(a0, b, acc[0][ct], 0, 0, 0);
        acc[1][ct] = __builtin_amdgcn_mfma_f32_16x16x32_bf16(a1, b, acc[1][ct], 0, 0, 0);
      }
    }
  }
  __syncthreads();

  // ---------------- epilogue1: Y1 = acc + bproj -> buf0 (bf16); stage W1T -> buf1 ----------------
#pragma unroll
  for (int ct = 0; ct < 8; ++ct) {
    const int col = ct * 16 + l16;
    const float bp = bproj[col];
#pragma unroll
    for (int rt = 0; rt < 2; ++rt)
#pragma unroll
      for (int r = 0; r < 4; ++r) {
        int row = w * 32 + rt * 16 + q * 4 + r;
        buf0[row * 128 + ((((col >> 3) ^ (row & 15)) << 3) + (col & 7))] = f2bf(acc[rt][ct][r] + bp);
      }
  }
#pragma unroll
  for (int it = 0; it < 8; ++it) {
    int i = tid + it * 256;
    int r = i >> 4, g = i & 15;
    *(uint4*)(buf1 + r * 128 + ((g ^ (r & 15)) << 3)) = *(const uint4*)(W1T + r * 128 + (g << 3));
  }
  __syncthreads();

  // ---------------- GEMM2: Y2 = relu(Y1 @ W1 + b1), K=128 ----------------
#pragma unroll
  for (int rt = 0; rt < 2; ++rt)
#pragma unroll
    for (int ct = 0; ct < 8; ++ct) acc[rt][ct] = (f32x4){0.f, 0.f, 0.f, 0.f};
#pragma unroll
  for (int ks = 0; ks < 4; ++ks) {
    bf16x8 a0 = *(const bf16x8*)(buf0 + (w * 32 + l16) * 128      + (((4 * ks + q) ^ l16) << 3));
    bf16x8 a1 = *(const bf16x8*)(buf0 + (w * 32 + 16 + l16) * 128 + (((4 * ks + q) ^ l16) << 3));
#pragma unroll
    for (int ct = 0; ct < 8; ++ct) {
      bf16x8 b = *(const bf16x8*)(buf1 + (ct * 16 + l16) * 128 + (((4 * ks + q) ^ l16) << 3));
      acc[0][ct] = __builtin_amdgcn_mfma_f32_16x16x32_bf16(a0, b, acc[0][ct], 0, 0, 0);
      acc[1][ct] = __builtin_amdgcn_mfma_f32_16x16x32_bf16(a1, b, acc[1][ct], 0, 0, 0);
    }
  }
  __syncthreads();

  // ---------------- epilogue2: relu -> buf0; stage W2T -> buf1 ----------------
#pragma unroll
  for (int ct = 0; ct < 8; ++ct) {
    const int col = ct * 16 + l16;
    const float bb = b1v[col];
#pragma unroll
    for (int rt = 0; rt < 2; ++rt)
#pragma unroll
      for (int r = 0; r < 4; ++r) {
        int row = w * 32 + rt * 16 + q * 4 + r;
        float v = acc[rt][ct][r] + bb;
        v = v > 0.f ? v : 0.f;
        buf0[row * 128 + ((((col >> 3) ^ (row & 15)) << 3) + (col & 7))] = f2bf(v);
      }
  }
#pragma unroll
  for (int it = 0; it < 8; ++it) {
    int i = tid + it * 256;
    int r = i >> 4, g = i & 15;
    *(uint4*)(buf1 + r * 128 + ((g ^ (r & 15)) << 3)) = *(const uint4*)(W2T + r * 128 + (g << 3));
  }
  __syncthreads();

  // ---------------- GEMM3: Y3 = Y2 @ W2 + b2, K=128 ----------------
#pragma unroll
  for (int rt = 0; rt < 2; ++rt)
#pragma unroll
    for (int ct = 0; ct < 8; ++ct) acc[rt][ct] = (f32x4){0.f, 0.f, 0.f, 0.f};
#pragma unroll
  for (int ks = 0; ks < 4; ++ks) {
    bf16x8 a0 = *(const bf16x8*)(buf0 + (w * 32 + l16) * 128      + (((4 * ks + q) ^ l16) << 3));
    bf16x8 a1 = *(const bf16x8*)(buf0 + (w * 32 + 16 + l16) * 128 + (((4 * ks + q) ^ l16) << 3));
#pragma unroll
    for (int ct = 0; ct < 8; ++ct) {
      bf16x8 b = *(const bf16x8*)(buf1 + (ct * 16 + l16) * 128 + (((4 * ks + q) ^ l16) << 3));
      acc[0][ct] = __builtin_amdgcn_mfma_f32_16x16x32_bf16(a0, b, acc[0][ct], 0, 0, 0);
      acc[1][ct] = __builtin_amdgcn_mfma_f32_16x16x32_bf16(a1, b, acc[1][ct], 0, 0, 0);
    }
  }
  __syncthreads();   // all GEMM3 LDS reads done before y3l overwrites both buffers

  // ---------------- epilogue3: +b2, per-block col-sums -> atomics, Y3 -> LDS -> d_out ----------------
#pragma unroll
  for (int ct = 0; ct < 8; ++ct) {
    const int col = ct * 16 + l16;
    const float bb = b2v[col];
    float s = 0.f;
#pragma unroll
    for (int rt = 0; rt < 2; ++rt)
#pragma unroll
      for (int r = 0; r < 4; ++r) {
        float v = acc[rt][ct][r] + bb;
        s += v;
        y3l[(w * 32 + rt * 16 + q * 4 + r) * 128 + col] = v;
      }
    s += __shfl_down(s, 16);
    s += __shfl_down(s, 32);
    if (lane < 16) atomicAdd(S + bidx * D_OUT + col, s);
  }
  __syncthreads();
#pragma unroll
  for (int it = 0; it < 16; ++it) {
    int i = tid + it * 256;
    int r = i >> 5, cc = (i & 31) << 2;
    *(float4*)(out + (size_t)(rowbase + r) * D_OUT + cc) = *(const float4*)(y3l + r * 128 + cc);
  }
}

// out[row][d] = S[b][d] - out[row][d], in place
__global__ __launch_bounds__(256) void finalize(float* __restrict__ out, const float* __restrict__ S) {
  size_t gid = (size_t)blockIdx.x * 256 + threadIdx.x;
  size_t flat = gid * 4;
  int d = (int)(flat & 127);
  int row = (int)(flat >> 7);
  int b = row >> 12;
  float4 sv = *(const float4*)(S + (b << 7) + d);
  float4 y = *(const float4*)(out + flat);
  float4 o; o.x = sv.x - y.x; o.y = sv.y - y.y; o.z = sv.z - y.z; o.w = sv.w - y.w;
  *(float4*)(out + flat) = o;
}

extern "C" void kernel_launch(void* const* d_in, const int* in_sizes, int n_in,
                              void* d_out, int out_size, void* d_ws, size_t ws_size,
                              hipStream_t stream) {
  const float* X  = (const float*)d_in[0];
  const float* Wp = (const float*)d_in[1];
  const float* bp = (const float*)d_in[2];
  const float* W1 = (const float*)d_in[3];
  const float* b1 = (const float*)d_in[4];
  const float* W2 = (const float*)d_in[5];
  const float* b2 = (const float*)d_in[6];
  float* out = (float*)d_out;

  char* ws = (char*)d_ws;
  float* S = (float*)ws;                                          // 8 KB
  unsigned short* WpT = (unsigned short*)(ws + 8192);             // 64 KB
  unsigned short* W1T = (unsigned short*)(ws + 8192 + 65536);     // 32 KB
  unsigned short* W2T = (unsigned short*)(ws + 8192 + 65536 + 32768);

  hipMemsetAsync(S, 0, NB * D_OUT * sizeof(float), stream);
  prep_weights<<<256, 256, 0, stream>>>(Wp, W1, W2, WpT, W1T, W2T);
  fused3<<<(NB * NSEQ) / TILE_M, 256, LDS_BYTES, stream>>>(X, WpT, W1T, W2T, bp, b1, b2, out, S);
  finalize<<<(NB * NSEQ * D_OUT) / (4 * 256), 256, 0, stream>>>(out, S);
}

// Round 3
// 147.806 us; speedup vs baseline: 1.0082x; 1.0082x over previous
//
#include <hip/hip_runtime.h>
#include <stdint.h>

#define D_IN  256
#define D_OUT 128
#define NSEQ  4096
#define NB    16
#define TILE_M 64
#define GRID_M ((NB * NSEQ) / TILE_M)   // 1024 blocks
#define LDS_BYTES 16384

typedef __bf16 bf16x8 __attribute__((ext_vector_type(8)));
typedef float  f32x4  __attribute__((ext_vector_type(4)));

__device__ __forceinline__ unsigned short f2bf(float f) {
  union { float f; unsigned int u; } a; a.f = f;
  unsigned int r = a.u + 0x7FFFu + ((a.u >> 16) & 1u);
  return (unsigned short)(r >> 16);
}
__device__ __forceinline__ float bf2f(unsigned short u) {
  union { unsigned int u; float f; } a; a.u = ((unsigned int)u) << 16;
  return a.f;
}

// Transpose+convert weights to bf16 [n][k] (k contiguous) in ws; block 0 zeroes S.
__global__ __launch_bounds__(256) void prep_weights(
    const float* __restrict__ Wp, const float* __restrict__ W1, const float* __restrict__ W2,
    unsigned short* __restrict__ WpT, unsigned short* __restrict__ W1T, unsigned short* __restrict__ W2T,
    float* __restrict__ S) {
  int t = blockIdx.x * 256 + threadIdx.x;
  if (blockIdx.x == 0) {
#pragma unroll
    for (int j = 0; j < 8; ++j) S[threadIdx.x + j * 256] = 0.f;
  }
  if (t < 256 * 128) {
    int k = t >> 7, n = t & 127;
    WpT[n * 256 + k] = f2bf(Wp[t]);
  } else if (t < 256 * 128 + 128 * 128) {
    int t2 = t - 256 * 128; int k = t2 >> 7, n = t2 & 127;
    W1T[n * 128 + k] = f2bf(W1[t2]);
  } else {
    int t3 = t - 256 * 128 - 128 * 128; int k = t3 >> 7, n = t3 & 127;
    W2T[n * 128 + k] = f2bf(W2[t3]);
  }
}

// 3 chained GEMMs per 64-row tile. A tile in 16KB swizzled LDS; B fragments
// loaded straight from L2-resident bf16 weights. Y3 + b2 summed into S
// (atomics) and written out: bf16 -> ws (USE_WS) or fp32 -> out (fallback).
// Wave w: row band rb=w>>1 (32 rows), col half ch=w&1 (64 cols).
// LDS swizzle: (row,col) -> row*128 + ((col>>3 ^ (row&15))<<3) + (col&7).
template <bool USE_WS>
__global__ __launch_bounds__(256, 4) void fused3(
    const float* __restrict__ X,
    const unsigned short* __restrict__ WpT,
    const unsigned short* __restrict__ W1T,
    const unsigned short* __restrict__ W2T,
    const float* __restrict__ bproj, const float* __restrict__ b1v, const float* __restrict__ b2v,
    unsigned short* __restrict__ Y3, float* __restrict__ out, float* __restrict__ S) {
  extern __shared__ char smem[];
  unsigned short* buf0 = (unsigned short*)smem;   // 64x128 bf16, swizzled

  const int tid  = threadIdx.x;
  const int lane = tid & 63;
  const int w    = tid >> 6;
  const int rb   = w >> 1;
  const int ch   = w & 1;
  const int q    = lane >> 4;
  const int l16  = lane & 15;
  const int rowbase = blockIdx.x * TILE_M;
  const int bidx = rowbase >> 12;

  f32x4 acc[2][4];

  // ---------------- GEMM1: Y1 = X @ Wp (K=256 in two 128-chunks) ----------------
#pragma unroll
  for (int rt = 0; rt < 2; ++rt)
#pragma unroll
    for (int ct = 0; ct < 4; ++ct) acc[rt][ct] = (f32x4){0.f, 0.f, 0.f, 0.f};

  for (int c = 0; c < 2; ++c) {
#pragma unroll
    for (int it = 0; it < 8; ++it) {
      int i = tid + it * 256;
      int r = i >> 5, c4 = (i & 31) << 2;
      const float4 v = *(const float4*)(X + (size_t)(rowbase + r) * D_IN + c * 128 + c4);
      ushort4 u; u.x = f2bf(v.x); u.y = f2bf(v.y); u.z = f2bf(v.z); u.w = f2bf(v.w);
      *(ushort4*)(buf0 + r * 128 + ((((c4 >> 3) ^ (r & 15)) << 3) + (c4 & 7))) = u;
    }
    __syncthreads();
#pragma unroll
    for (int ks = 0; ks < 4; ++ks) {
      bf16x8 a0 = *(const bf16x8*)(buf0 + (rb * 32 + l16) * 128      + (((4 * ks + q) ^ l16) << 3));
      bf16x8 a1 = *(const bf16x8*)(buf0 + (rb * 32 + 16 + l16) * 128 + (((4 * ks + q) ^ l16) << 3));
#pragma unroll
      for (int ct = 0; ct < 4; ++ct) {
        bf16x8 b = *(const bf16x8*)(WpT + (size_t)(ch * 64 + ct * 16 + l16) * 256 + c * 128 + ks * 32 + q * 8);
        acc[0][ct] = __builtin_amdgcn_mfma_f32_16x16x32_bf16(a0, b, acc[0][ct], 0, 0, 0);
        acc[1][ct] = __builtin_amdgcn_mfma_f32_16x16x32_bf16(a1, b, acc[1][ct], 0, 0, 0);
      }
    }
    __syncthreads();
  }

  // ---------------- epilogue1: Y1 = acc + bproj -> buf0 bf16 ----------------
#pragma unroll
  for (int ct = 0; ct < 4; ++ct) {
    const int col = ch * 64 + ct * 16 + l16;
    const float bp = bproj[col];
#pragma unroll
    for (int rt = 0; rt < 2; ++rt)
#pragma unroll
      for (int r = 0; r < 4; ++r) {
        int row = rb * 32 + rt * 16 + q * 4 + r;
        buf0[row * 128 + ((((col >> 3) ^ (row & 15)) << 3) + (col & 7))] = f2bf(acc[rt][ct][r] + bp);
      }
  }
  __syncthreads();

  // ---------------- GEMM2: Y2 = relu(Y1 @ W1 + b1), K=128 ----------------
#pragma unroll
  for (int rt = 0; rt < 2; ++rt)
#pragma unroll
    for (int ct = 0; ct < 4; ++ct) acc[rt][ct] = (f32x4){0.f, 0.f, 0.f, 0.f};
#pragma unroll
  for (int ks = 0; ks < 4; ++ks) {
    bf16x8 a0 = *(const bf16x8*)(buf0 + (rb * 32 + l16) * 128      + (((4 * ks + q) ^ l16) << 3));
    bf16x8 a1 = *(const bf16x8*)(buf0 + (rb * 32 + 16 + l16) * 128 + (((4 * ks + q) ^ l16) << 3));
#pragma unroll
    for (int ct = 0; ct < 4; ++ct) {
      bf16x8 b = *(const bf16x8*)(W1T + (size_t)(ch * 64 + ct * 16 + l16) * 128 + ks * 32 + q * 8);
      acc[0][ct] = __builtin_amdgcn_mfma_f32_16x16x32_bf16(a0, b, acc[0][ct], 0, 0, 0);
      acc[1][ct] = __builtin_amdgcn_mfma_f32_16x16x32_bf16(a1, b, acc[1][ct], 0, 0, 0);
    }
  }
  __syncthreads();

  // ---------------- epilogue2: relu(acc + b1) -> buf0 bf16 ----------------
#pragma unroll
  for (int ct = 0; ct < 4; ++ct) {
    const int col = ch * 64 + ct * 16 + l16;
    const float bb = b1v[col];
#pragma unroll
    for (int rt = 0; rt < 2; ++rt)
#pragma unroll
      for (int r = 0; r < 4; ++r) {
        int row = rb * 32 + rt * 16 + q * 4 + r;
        float v = acc[rt][ct][r] + bb;
        v = v > 0.f ? v : 0.f;
        buf0[row * 128 + ((((col >> 3) ^ (row & 15)) << 3) + (col & 7))] = f2bf(v);
      }
  }
  __syncthreads();

  // ---------------- GEMM3: Y3 = Y2 @ W2, K=128 ----------------
#pragma unroll
  for (int rt = 0; rt < 2; ++rt)
#pragma unroll
    for (int ct = 0; ct < 4; ++ct) acc[rt][ct] = (f32x4){0.f, 0.f, 0.f, 0.f};
#pragma unroll
  for (int ks = 0; ks < 4; ++ks) {
    bf16x8 a0 = *(const bf16x8*)(buf0 + (rb * 32 + l16) * 128      + (((4 * ks + q) ^ l16) << 3));
    bf16x8 a1 = *(const bf16x8*)(buf0 + (rb * 32 + 16 + l16) * 128 + (((4 * ks + q) ^ l16) << 3));
#pragma unroll
    for (int ct = 0; ct < 4; ++ct) {
      bf16x8 b = *(const bf16x8*)(W2T + (size_t)(ch * 64 + ct * 16 + l16) * 128 + ks * 32 + q * 8);
      acc[0][ct] = __builtin_amdgcn_mfma_f32_16x16x32_bf16(a0, b, acc[0][ct], 0, 0, 0);
      acc[1][ct] = __builtin_amdgcn_mfma_f32_16x16x32_bf16(a1, b, acc[1][ct], 0, 0, 0);
    }
  }
  __syncthreads();   // all GEMM3 LDS reads done before buf0 is overwritten

  // ---------------- epilogue3: Y3 = acc + b2 -> buf0 (swizzled bf16); col sums -> S ----------------
#pragma unroll
  for (int ct = 0; ct < 4; ++ct) {
    const int col = ch * 64 + ct * 16 + l16;
    const float bb = b2v[col];
    float s = 0.f;
#pragma unroll
    for (int rt = 0; rt < 2; ++rt)
#pragma unroll
      for (int r = 0; r < 4; ++r) {
        float v = acc[rt][ct][r] + bb;
        s += v;
        int row = rb * 32 + rt * 16 + q * 4 + r;
        buf0[row * 128 + ((((col >> 3) ^ (row & 15)) << 3) + (col & 7))] = f2bf(v);
      }
    s += __shfl_down(s, 16);
    s += __shfl_down(s, 32);
    if (lane < 16) atomicAdd(S + bidx * D_OUT + col, s);
  }
  __syncthreads();

  // ---------------- copy-out: un-swizzle LDS -> global ----------------
  if (USE_WS) {
    // 64 rows x 16 granules of 16B -> bf16 Y3 in ws, coalesced dwordx4
#pragma unroll
    for (int it = 0; it < 4; ++it) {
      int i = tid + it * 256;
      int r = i >> 4, g = i & 15;
      *(uint4*)(Y3 + (size_t)(rowbase + r) * 128 + g * 8) =
          *(const uint4*)(buf0 + r * 128 + ((g ^ (r & 15)) << 3));
    }
  } else {
    // widen bf16 -> fp32 into out (finalized in place by a second kernel)
#pragma unroll
    for (int it = 0; it < 8; ++it) {
      int i = tid + it * 256;
      int r = i >> 5, c4 = (i & 31) << 2;
      ushort4 u = *(const ushort4*)(buf0 + r * 128 + ((((c4 >> 3) ^ (r & 15)) << 3) + (c4 & 7)));
      float4 v; v.x = bf2f(u.x); v.y = bf2f(u.y); v.z = bf2f(u.z); v.w = bf2f(u.w);
      *(float4*)(out + (size_t)(rowbase + r) * D_OUT + c4) = v;
    }
  }
}

// out[row][d] = S[b][d] - Y3_bf16[row][d]; 8 elems/thread
__global__ __launch_bounds__(256) void finalize_ws(
    float* __restrict__ out, const unsigned short* __restrict__ Y3, const float* __restrict__ S) {
  size_t g = (size_t)blockIdx.x * 256 + threadIdx.x;
  size_t base = g * 8;
  int row = (int)(base >> 7);
  int col = (int)(base & 127);
  int b = row >> 12;
  uint4 u = *(const uint4*)(Y3 + base);
  float4 s0 = *(const float4*)(S + (b << 7) + col);
  float4 s1 = *(const float4*)(S + (b << 7) + col + 4);
  union { unsigned int u; float f; } t;
  float4 o0, o1;
  t.u = u.x << 16;          o0.x = s0.x - t.f;
  t.u = u.x & 0xFFFF0000u;  o0.y = s0.y - t.f;
  t.u = u.y << 16;          o0.z = s0.z - t.f;
  t.u = u.y & 0xFFFF0000u;  o0.w = s0.w - t.f;
  t.u = u.z << 16;          o1.x = s1.x - t.f;
  t.u = u.z & 0xFFFF0000u;  o1.y = s1.y - t.f;
  t.u = u.w << 16;          o1.z = s1.z - t.f;
  t.u = u.w & 0xFFFF0000u;  o1.w = s1.w - t.f;
  *(float4*)(out + base) = o0;
  *(float4*)(out + base + 4) = o1;
}

// fallback: out[row][d] = S[b][d] - out[row][d], in place
__global__ __launch_bounds__(256) void finalize_ip(float* __restrict__ out, const float* __restrict__ S) {
  size_t g = (size_t)blockIdx.x * 256 + threadIdx.x;
  size_t base = g * 8;
  int row = (int)(base >> 7);
  int col = (int)(base & 127);
  int b = row >> 12;
  float4 s0 = *(const float4*)(S + (b << 7) + col);
  float4 s1 = *(const float4*)(S + (b << 7) + col + 4);
  float4 y0 = *(const float4*)(out + base);
  float4 y1 = *(const float4*)(out + base + 4);
  float4 o0, o1;
  o0.x = s0.x - y0.x; o0.y = s0.y - y0.y; o0.z = s0.z - y0.z; o0.w = s0.w - y0.w;
  o1.x = s1.x - y1.x; o1.y = s1.y - y1.y; o1.z = s1.z - y1.z; o1.w = s1.w - y1.w;
  *(float4*)(out + base) = o0;
  *(float4*)(out + base + 4) = o1;
}

extern "C" void kernel_launch(void* const* d_in, const int* in_sizes, int n_in,
                              void* d_out, int out_size, void* d_ws, size_t ws_size,
                              hipStream_t stream) {
  const float* X  = (const float*)d_in[0];
  const float* Wp = (const float*)d_in[1];
  const float* bp = (const float*)d_in[2];
  const float* W1 = (const float*)d_in[3];
  const float* b1 = (const float*)d_in[4];
  const float* W2 = (const float*)d_in[5];
  const float* b2 = (const float*)d_in[6];
  float* out = (float*)d_out;

  char* ws = (char*)d_ws;
  float* S = (float*)ws;                                          // 8 KB
  unsigned short* WpT = (unsigned short*)(ws + 8192);             // 64 KB
  unsigned short* W1T = (unsigned short*)(ws + 8192 + 65536);     // 32 KB
  unsigned short* W2T = (unsigned short*)(ws + 8192 + 65536 + 32768);
  unsigned short* Y3  = (unsigned short*)(ws + 8192 + 131072);    // 16 MB

  const size_t need = 8192 + 131072 + (size_t)NB * NSEQ * D_OUT * 2;
  const bool use_ws = ws_size >= need;

  prep_weights<<<256, 256, 0, stream>>>(Wp, W1, W2, WpT, W1T, W2T, S);

  const int fin_blocks = (NB * NSEQ * D_OUT) / (8 * 256);  // 4096
  if (use_ws) {
    fused3<true><<<GRID_M, 256, LDS_BYTES, stream>>>(X, WpT, W1T, W2T, bp, b1, b2, Y3, out, S);
    finalize_ws<<<fin_blocks, 256, 0, stream>>>(out, Y3, S);
  } else {
    fused3<false><<<GRID_M, 256, LDS_BYTES, stream>>>(X, WpT, W1T, W2T, bp, b1, b2, Y3, out, S);
    finalize_ip<<<fin_blocks, 256, 0, stream>>>(out, S);
  }
}

// Round 4
// 138.385 us; speedup vs baseline: 1.0768x; 1.0681x over previous
//
#include <hip/hip_runtime.h>
#include <stdint.h>

#define D_IN  256
#define D_OUT 128
#define NSEQ  4096
#define NB    16
#define TILE_M 64
#define GRID_M ((NB * NSEQ) / TILE_M)   // 1024 blocks
#define LDS_BYTES 16384

typedef __bf16 bf16x8 __attribute__((ext_vector_type(8)));
typedef float  f32x4  __attribute__((ext_vector_type(4)));

__device__ __forceinline__ unsigned short f2bf(float f) {
  union { float f; unsigned int u; } a; a.f = f;
  unsigned int r = a.u + 0x7FFFu + ((a.u >> 16) & 1u);
  return (unsigned short)(r >> 16);
}
__device__ __forceinline__ float bf2f(unsigned short u) {
  union { unsigned int u; float f; } a; a.u = ((unsigned int)u) << 16;
  return a.f;
}

// Transpose+convert weights to bf16 [n][k] (k contiguous) in ws.
__global__ __launch_bounds__(256) void prep_weights(
    const float* __restrict__ Wp, const float* __restrict__ W1, const float* __restrict__ W2,
    unsigned short* __restrict__ WpT, unsigned short* __restrict__ W1T, unsigned short* __restrict__ W2T) {
  int t = blockIdx.x * 256 + threadIdx.x;
  if (t < 256 * 128) {
    int k = t >> 7, n = t & 127;
    WpT[n * 256 + k] = f2bf(Wp[t]);
  } else if (t < 256 * 128 + 128 * 128) {
    int t2 = t - 256 * 128; int k = t2 >> 7, n = t2 & 127;
    W1T[n * 128 + k] = f2bf(W1[t2]);
  } else {
    int t3 = t - 256 * 128 - 128 * 128; int k = t3 >> 7, n = t3 & 127;
    W2T[n * 128 + k] = f2bf(W2[t3]);
  }
}

// 3 chained GEMMs per 64-row tile. A tile in swizzled LDS; B fragments
// preloaded into registers one GEMM ahead (no global latency inside MFMA
// loops). Wave w covers ALL 64 rows x 32 cols [w*32, w*32+32).
// No atomics: per-block column sums -> P[block][128].
// LDS swizzle: (row,col) -> row*128 + ((col>>3 ^ (row&15))<<3) + (col&7).
template <bool USE_WS>
__global__ __launch_bounds__(256, 3) void fused3(
    const float* __restrict__ X,
    const unsigned short* __restrict__ WpT,
    const unsigned short* __restrict__ W1T,
    const unsigned short* __restrict__ W2T,
    const float* __restrict__ bproj, const float* __restrict__ b1v, const float* __restrict__ b2v,
    unsigned short* __restrict__ Y3, float* __restrict__ out, float* __restrict__ P) {
  extern __shared__ char smem[];
  unsigned short* buf0 = (unsigned short*)smem;   // 64x128 bf16, swizzled

  const int tid  = threadIdx.x;
  const int lane = tid & 63;
  const int w    = tid >> 6;
  const int q    = lane >> 4;
  const int l16  = lane & 15;
  const int rowbase = blockIdx.x * TILE_M;

  const int col0 = w * 32 + l16;        // ct=0 column
  const int col1 = col0 + 16;           // ct=1 column

  f32x4 acc[4][2];
  bf16x8 bA[8], bB[8];                  // [ks*2 + ct]

  // ---- preload Wp chunk0 B-frags into bA ----
#pragma unroll
  for (int ks = 0; ks < 4; ++ks) {
    bA[ks * 2 + 0] = *(const bf16x8*)(WpT + (size_t)col0 * 256 + ks * 32 + q * 8);
    bA[ks * 2 + 1] = *(const bf16x8*)(WpT + (size_t)col1 * 256 + ks * 32 + q * 8);
  }

  // ---- stage X chunk0 (fp32 -> bf16, swizzled) ----
#pragma unroll
  for (int it = 0; it < 8; ++it) {
    int i = tid + it * 256;
    int r = i >> 5, c4 = (i & 31) << 2;
    const float4 v = *(const float4*)(X + (size_t)(rowbase + r) * D_IN + c4);
    ushort4 u; u.x = f2bf(v.x); u.y = f2bf(v.y); u.z = f2bf(v.z); u.w = f2bf(v.w);
    *(ushort4*)(buf0 + r * 128 + ((((c4 >> 3) ^ (r & 15)) << 3) + (c4 & 7))) = u;
  }

#pragma unroll
  for (int rt = 0; rt < 4; ++rt)
#pragma unroll
    for (int ct = 0; ct < 2; ++ct) acc[rt][ct] = (f32x4){0.f, 0.f, 0.f, 0.f};

  __syncthreads();

  // ---- prefetch Wp chunk1 into bB (covered by GEMM1-c0 compute) ----
#pragma unroll
  for (int ks = 0; ks < 4; ++ks) {
    bB[ks * 2 + 0] = *(const bf16x8*)(WpT + (size_t)col0 * 256 + 128 + ks * 32 + q * 8);
    bB[ks * 2 + 1] = *(const bf16x8*)(WpT + (size_t)col1 * 256 + 128 + ks * 32 + q * 8);
  }

  // ---- GEMM1 chunk0 ----
#pragma unroll
  for (int ks = 0; ks < 4; ++ks) {
#pragma unroll
    for (int rt = 0; rt < 4; ++rt) {
      bf16x8 a = *(const bf16x8*)(buf0 + (rt * 16 + l16) * 128 + (((4 * ks + q) ^ l16) << 3));
      acc[rt][0] = __builtin_amdgcn_mfma_f32_16x16x32_bf16(a, bA[ks * 2 + 0], acc[rt][0], 0, 0, 0);
      acc[rt][1] = __builtin_amdgcn_mfma_f32_16x16x32_bf16(a, bA[ks * 2 + 1], acc[rt][1], 0, 0, 0);
    }
  }
  __syncthreads();

  // ---- stage X chunk1 ----
#pragma unroll
  for (int it = 0; it < 8; ++it) {
    int i = tid + it * 256;
    int r = i >> 5, c4 = (i & 31) << 2;
    const float4 v = *(const float4*)(X + (size_t)(rowbase + r) * D_IN + 128 + c4);
    ushort4 u; u.x = f2bf(v.x); u.y = f2bf(v.y); u.z = f2bf(v.z); u.w = f2bf(v.w);
    *(ushort4*)(buf0 + r * 128 + ((((c4 >> 3) ^ (r & 15)) << 3) + (c4 & 7))) = u;
  }
  __syncthreads();

  // ---- prefetch W1 into bA (Wp-c0 frags are dead now) ----
#pragma unroll
  for (int ks = 0; ks < 4; ++ks) {
    bA[ks * 2 + 0] = *(const bf16x8*)(W1T + (size_t)col0 * 128 + ks * 32 + q * 8);
    bA[ks * 2 + 1] = *(const bf16x8*)(W1T + (size_t)col1 * 128 + ks * 32 + q * 8);
  }

  // ---- GEMM1 chunk1 (bB) ----
#pragma unroll
  for (int ks = 0; ks < 4; ++ks) {
#pragma unroll
    for (int rt = 0; rt < 4; ++rt) {
      bf16x8 a = *(const bf16x8*)(buf0 + (rt * 16 + l16) * 128 + (((4 * ks + q) ^ l16) << 3));
      acc[rt][0] = __builtin_amdgcn_mfma_f32_16x16x32_bf16(a, bB[ks * 2 + 0], acc[rt][0], 0, 0, 0);
      acc[rt][1] = __builtin_amdgcn_mfma_f32_16x16x32_bf16(a, bB[ks * 2 + 1], acc[rt][1], 0, 0, 0);
    }
  }
  __syncthreads();

  // ---- epilogue1: Y1 = acc + bproj -> buf0 bf16 ----
  {
    const float bp0 = bproj[col0], bp1 = bproj[col1];
#pragma unroll
    for (int rt = 0; rt < 4; ++rt)
#pragma unroll
      for (int r = 0; r < 4; ++r) {
        int row = rt * 16 + q * 4 + r;
        int sw = (row & 15) << 3;
        buf0[row * 128 + ((((col0 >> 3) << 3) ^ sw) + (col0 & 7))] = f2bf(acc[rt][0][r] + bp0);
        buf0[row * 128 + ((((col1 >> 3) << 3) ^ sw) + (col1 & 7))] = f2bf(acc[rt][1][r] + bp1);
      }
  }
  __syncthreads();

  // ---- prefetch W2 into bB ----
#pragma unroll
  for (int ks = 0; ks < 4; ++ks) {
    bB[ks * 2 + 0] = *(const bf16x8*)(W2T + (size_t)col0 * 128 + ks * 32 + q * 8);
    bB[ks * 2 + 1] = *(const bf16x8*)(W2T + (size_t)col1 * 128 + ks * 32 + q * 8);
  }

  // ---- GEMM2: Y2 = relu(Y1 @ W1 + b1) ----
#pragma unroll
  for (int rt = 0; rt < 4; ++rt)
#pragma unroll
    for (int ct = 0; ct < 2; ++ct) acc[rt][ct] = (f32x4){0.f, 0.f, 0.f, 0.f};
#pragma unroll
  for (int ks = 0; ks < 4; ++ks) {
#pragma unroll
    for (int rt = 0; rt < 4; ++rt) {
      bf16x8 a = *(const bf16x8*)(buf0 + (rt * 16 + l16) * 128 + (((4 * ks + q) ^ l16) << 3));
      acc[rt][0] = __builtin_amdgcn_mfma_f32_16x16x32_bf16(a, bA[ks * 2 + 0], acc[rt][0], 0, 0, 0);
      acc[rt][1] = __builtin_amdgcn_mfma_f32_16x16x32_bf16(a, bA[ks * 2 + 1], acc[rt][1], 0, 0, 0);
    }
  }
  __syncthreads();

  // ---- epilogue2: relu(acc + b1) -> buf0 bf16 ----
  {
    const float bb0 = b1v[col0], bb1 = b1v[col1];
#pragma unroll
    for (int rt = 0; rt < 4; ++rt)
#pragma unroll
      for (int r = 0; r < 4; ++r) {
        int row = rt * 16 + q * 4 + r;
        int sw = (row & 15) << 3;
        float v0 = acc[rt][0][r] + bb0; v0 = v0 > 0.f ? v0 : 0.f;
        float v1 = acc[rt][1][r] + bb1; v1 = v1 > 0.f ? v1 : 0.f;
        buf0[row * 128 + ((((col0 >> 3) << 3) ^ sw) + (col0 & 7))] = f2bf(v0);
        buf0[row * 128 + ((((col1 >> 3) << 3) ^ sw) + (col1 & 7))] = f2bf(v1);
      }
  }
  __syncthreads();

  // ---- GEMM3: Y3 = Y2 @ W2 (bB) ----
#pragma unroll
  for (int rt = 0; rt < 4; ++rt)
#pragma unroll
    for (int ct = 0; ct < 2; ++ct) acc[rt][ct] = (f32x4){0.f, 0.f, 0.f, 0.f};
#pragma unroll
  for (int ks = 0; ks < 4; ++ks) {
#pragma unroll
    for (int rt = 0; rt < 4; ++rt) {
      bf16x8 a = *(const bf16x8*)(buf0 + (rt * 16 + l16) * 128 + (((4 * ks + q) ^ l16) << 3));
      acc[rt][0] = __builtin_amdgcn_mfma_f32_16x16x32_bf16(a, bB[ks * 2 + 0], acc[rt][0], 0, 0, 0);
      acc[rt][1] = __builtin_amdgcn_mfma_f32_16x16x32_bf16(a, bB[ks * 2 + 1], acc[rt][1], 0, 0, 0);
    }
  }
  __syncthreads();   // all GEMM3 LDS reads done before buf0 overwrite

  // ---- epilogue3: Y3 = acc + b2 -> buf0 bf16; per-block col sums -> P ----
  {
    const float bb0 = b2v[col0], bb1 = b2v[col1];
    float s0 = 0.f, s1 = 0.f;
#pragma unroll
    for (int rt = 0; rt < 4; ++rt)
#pragma unroll
      for (int r = 0; r < 4; ++r) {
        int row = rt * 16 + q * 4 + r;
        int sw = (row & 15) << 3;
        float v0 = acc[rt][0][r] + bb0;
        float v1 = acc[rt][1][r] + bb1;
        s0 += v0; s1 += v1;
        buf0[row * 128 + ((((col0 >> 3) << 3) ^ sw) + (col0 & 7))] = f2bf(v0);
        buf0[row * 128 + ((((col1 >> 3) << 3) ^ sw) + (col1 & 7))] = f2bf(v1);
      }
    s0 += __shfl_down(s0, 16); s0 += __shfl_down(s0, 32);
    s1 += __shfl_down(s1, 16); s1 += __shfl_down(s1, 32);
    if (lane < 16) {
      P[(size_t)blockIdx.x * 128 + col0] = s0;
      P[(size_t)blockIdx.x * 128 + col1] = s1;
    }
  }
  __syncthreads();

  // ---- copy-out: un-swizzle LDS -> global ----
  if (USE_WS) {
#pragma unroll
    for (int it = 0; it < 4; ++it) {
      int i = tid + it * 256;
      int r = i >> 4, g = i & 15;
      *(uint4*)(Y3 + (size_t)(rowbase + r) * 128 + g * 8) =
          *(const uint4*)(buf0 + r * 128 + ((g ^ (r & 15)) << 3));
    }
  } else {
#pragma unroll
    for (int it = 0; it < 8; ++it) {
      int i = tid + it * 256;
      int r = i >> 5, c4 = (i & 31) << 2;
      ushort4 u = *(const ushort4*)(buf0 + r * 128 + ((((c4 >> 3) ^ (r & 15)) << 3) + (c4 & 7)));
      float4 v; v.x = bf2f(u.x); v.y = bf2f(u.y); v.z = bf2f(u.z); v.w = bf2f(u.w);
      *(float4*)(out + (size_t)(rowbase + r) * D_OUT + c4) = v;
    }
  }
}

// S[b][col] = sum of P over the 64 blocks of batch b. 16 blocks x 256 thr.
__global__ __launch_bounds__(256) void reduce_S(const float* __restrict__ P, float* __restrict__ S) {
  __shared__ float tmp[128];
  int b = blockIdx.x;
  int col = threadIdx.x & 127;
  int h = threadIdx.x >> 7;
  float s = 0.f;
#pragma unroll
  for (int i = 0; i < 32; ++i) s += P[(size_t)(b * 64 + h * 32 + i) * 128 + col];
  if (h == 1) tmp[col] = s;
  __syncthreads();
  if (h == 0) S[b * 128 + col] = s + tmp[col];
}

// out[row][d] = S[b][d] - Y3_bf16[row][d]; 8 elems/thread
__global__ __launch_bounds__(256) void finalize_ws(
    float* __restrict__ out, const unsigned short* __restrict__ Y3, const float* __restrict__ S) {
  size_t g = (size_t)blockIdx.x * 256 + threadIdx.x;
  size_t base = g * 8;
  int row = (int)(base >> 7);
  int col = (int)(base & 127);
  int b = row >> 12;
  uint4 u = *(const uint4*)(Y3 + base);
  float4 s0 = *(const float4*)(S + (b << 7) + col);
  float4 s1 = *(const float4*)(S + (b << 7) + col + 4);
  union { unsigned int u; float f; } t;
  float4 o0, o1;
  t.u = u.x << 16;          o0.x = s0.x - t.f;
  t.u = u.x & 0xFFFF0000u;  o0.y = s0.y - t.f;
  t.u = u.y << 16;          o0.z = s0.z - t.f;
  t.u = u.y & 0xFFFF0000u;  o0.w = s0.w - t.f;
  t.u = u.z << 16;          o1.x = s1.x - t.f;
  t.u = u.z & 0xFFFF0000u;  o1.y = s1.y - t.f;
  t.u = u.w << 16;          o1.z = s1.z - t.f;
  t.u = u.w & 0xFFFF0000u;  o1.w = s1.w - t.f;
  *(float4*)(out + base) = o0;
  *(float4*)(out + base + 4) = o1;
}

// fallback: out[row][d] = S[b][d] - out[row][d], in place
__global__ __launch_bounds__(256) void finalize_ip(float* __restrict__ out, const float* __restrict__ S) {
  size_t g = (size_t)blockIdx.x * 256 + threadIdx.x;
  size_t base = g * 8;
  int row = (int)(base >> 7);
  int col = (int)(base & 127);
  int b = row >> 12;
  float4 s0 = *(const float4*)(S + (b << 7) + col);
  float4 s1 = *(const float4*)(S + (b << 7) + col + 4);
  float4 y0 = *(const float4*)(out + base);
  float4 y1 = *(const float4*)(out + base + 4);
  float4 o0, o1;
  o0.x = s0.x - y0.x; o0.y = s0.y - y0.y; o0.z = s0.z - y0.z; o0.w = s0.w - y0.w;
  o1.x = s1.x - y1.x; o1.y = s1.y - y1.y; o1.z = s1.z - y1.z; o1.w = s1.w - y1.w;
  *(float4*)(out + base) = o0;
  *(float4*)(out + base + 4) = o1;
}

extern "C" void kernel_launch(void* const* d_in, const int* in_sizes, int n_in,
                              void* d_out, int out_size, void* d_ws, size_t ws_size,
                              hipStream_t stream) {
  const float* X  = (const float*)d_in[0];
  const float* Wp = (const float*)d_in[1];
  const float* bp = (const float*)d_in[2];
  const float* W1 = (const float*)d_in[3];
  const float* b1 = (const float*)d_in[4];
  const float* W2 = (const float*)d_in[5];
  const float* b2 = (const float*)d_in[6];
  float* out = (float*)d_out;

  char* ws = (char*)d_ws;
  float* S = (float*)ws;                                          // 8 KB
  unsigned short* WpT = (unsigned short*)(ws + 8192);             // 64 KB
  unsigned short* W1T = (unsigned short*)(ws + 8192 + 65536);     // 32 KB
  unsigned short* W2T = (unsigned short*)(ws + 8192 + 65536 + 32768);
  float* P = (float*)(ws + 8192 + 131072);                        // 512 KB
  unsigned short* Y3 = (unsigned short*)(ws + 8192 + 131072 + 524288);  // 16 MB

  const size_t need = 8192 + 131072 + 524288 + (size_t)NB * NSEQ * D_OUT * 2;
  const bool use_ws = ws_size >= need;

  prep_weights<<<256, 256, 0, stream>>>(Wp, W1, W2, WpT, W1T, W2T);

  const int fin_blocks = (NB * NSEQ * D_OUT) / (8 * 256);  // 4096
  if (use_ws) {
    fused3<true><<<GRID_M, 256, LDS_BYTES, stream>>>(X, WpT, W1T, W2T, bp, b1, b2, Y3, out, P);
    reduce_S<<<NB, 256, 0, stream>>>(P, S);
    finalize_ws<<<fin_blocks, 256, 0, stream>>>(out, Y3, S);
  } else {
    fused3<false><<<GRID_M, 256, LDS_BYTES, stream>>>(X, WpT, W1T, W2T, bp, b1, b2, Y3, out, P);
    reduce_S<<<NB, 256, 0, stream>>>(P, S);
    finalize_ip<<<fin_blocks, 256, 0, stream>>>(out, S);
  }
}